// Round 5
// baseline (549.833 us; speedup 1.0000x reference)
//
#include <hip/hip_runtime.h>
#include <stdint.h>

// GalerkinBlock: x -> LN1 -> qkv -> [fused LN(k),LN(v)+ctx=K^T V] -> [attn+proj
//   fused: x1 = q @ (ctx_scaled @ proj_w) + proj_b + x] -> LN2 -> mlp -> x1+mlp
// B=4 N=8192 C=512 H=4 D=128 HID=2048. All GEMMs bf16 MFMA (16x16x32), fp32 accum.
// Big GEMMs: 256x256 tile, BK=64, 8 waves, dbuf LDS (128 KiB), 4-phase interleave,
// counted vmcnt(4) (T4), XOR bank swizzle (T2), setprio (T5), XCD swizzle (T1).
// MODE 3 uses swapped MFMA (vector f32x4 epilogue, measured r4 win); MODES 1/2
// use unswapped + scalar bf16 epilogue (r4 swap regressed mlp1 94->106us).
// kT/vT intermediates eliminated: lnkv_ctx fuses LN+outer-product accumulation.

#define B_    4
#define N_    8192
#define C_    512
#define H_    4
#define D_    128
#define HID_  2048
#define M_    (B_*N_)          // 32768 rows
#define EPS_  1e-5f
#define SCALE_ 0.08838834764831845f   // D^-0.5

typedef unsigned short u16;
typedef unsigned int u32;
typedef __attribute__((ext_vector_type(8))) __bf16 bfrag_t;  // MFMA A/B frag (4 VGPRs)
typedef __attribute__((ext_vector_type(4))) float  f4_t;     // MFMA C/D frag
typedef __attribute__((ext_vector_type(2))) u32    u32x2;

__device__ __forceinline__ float bf2f(u16 a) {
    u32 u = ((u32)a) << 16; float f;
    __builtin_memcpy(&f, &u, 4); return f;
}
__device__ __forceinline__ u16 f2bf(float f) {                // RNE (cold paths)
    u32 u; __builtin_memcpy(&u, &f, 4);
    u += 0x7FFFu + ((u >> 16) & 1u);
    return (u16)(u >> 16);
}
__device__ __forceinline__ u16 f2bf_fast(float f) {           // round-half-up (hot epilogue)
    u32 u; __builtin_memcpy(&u, &f, 4);
    return (u16)((u + 0x8000u) >> 16);
}

// branch-free tanh-approx GELU
__device__ __forceinline__ float fast_gelu(float x) {
    const float kA = 2.3022084f;   // 2*0.7978845608*log2(e)
    const float kB = 0.1029435f;   // kA*0.044715
    float x2 = x * x;
    float e1 = __builtin_amdgcn_exp2f(x * (kB * x2 + kA));
    return x - x * __builtin_amdgcn_rcpf(e1 + 1.0f);
}

// async 16B global->LDS (lands at wave-uniform ldsbase + lane*16)
__device__ __forceinline__ void gld16(u16* lds, const u16* g) {
    void* gp = const_cast<u16*>(g);
    __builtin_amdgcn_global_load_lds((__attribute__((address_space(1))) void*)gp,
                                     (__attribute__((address_space(3))) void*)lds,
                                     16, 0, 0);
}

// ------- weight transpose+convert: fp32 [K,Ncols] -> bf16 [Ncols,K], LDS-tiled --
__global__ __launch_bounds__(256)
void wtrans(const float* __restrict__ in, u16* __restrict__ out,
            int K, int Ncols) {
    const int nb = Ncols >> 6;
    const int k0 = (blockIdx.x / nb) << 6, n0 = (blockIdx.x % nb) << 6;
    __shared__ u16 tile[64][65];
    const int tx = threadIdx.x & 63, ty = threadIdx.x >> 6;
    #pragma unroll
    for (int r = 0; r < 16; ++r) {
        int k = ty + r * 4;
        tile[k][tx] = f2bf(in[(long)(k0 + k) * Ncols + n0 + tx]);
    }
    __syncthreads();
    #pragma unroll
    for (int r = 0; r < 16; ++r) {
        int n = ty + r * 4;
        out[(long)(n0 + n) * K + k0 + tx] = tile[tx][n];
    }
}

// ---------------- row LayerNorm over 512 fp32 -> bf16 --------------------------
__global__ __launch_bounds__(256)
void ln_rows(const float* __restrict__ in, const float* __restrict__ w,
             const float* __restrict__ b, u16* __restrict__ out) {
    long row = blockIdx.x;
    int t = threadIdx.x;
    const float* p = in + row * 512;
    float v0 = p[t], v1 = p[t + 256];
    float s = v0 + v1, q = v0 * v0 + v1 * v1;
    #pragma unroll
    for (int o = 32; o >= 1; o >>= 1) { s += __shfl_xor(s, o, 64); q += __shfl_xor(q, o, 64); }
    __shared__ float sh[8];
    int wv = t >> 6, l = t & 63;
    if (l == 0) { sh[wv] = s; sh[4 + wv] = q; }
    __syncthreads();
    s = sh[0] + sh[1] + sh[2] + sh[3];
    q = sh[4] + sh[5] + sh[6] + sh[7];
    float mu = s * (1.f / 512.f);
    float var = q * (1.f / 512.f) - mu * mu;
    float rs = rsqrtf(var + EPS_);
    out[row * 512 + t]       = f2bf((v0 - mu) * rs * w[t] + b[t]);
    out[row * 512 + t + 256] = f2bf((v1 - mu) * rs * w[t + 256] + b[t + 256]);
}

// ------- fused LN(k),LN(v) + ctx partial: ctxP[bh][nc] += K_ln^T V_ln ----------
// grid (16 bh, 32 n-chunks of 256). Per sub-slice of 64 rows: LN k,v into
// transposed LDS tiles [128 d][72 n-stride] (stride 72*2B = 16B-aligned frags),
// then MFMA outer-product accumulate 128x128. 4 sub-slices -> f32 partial store.
__global__ __launch_bounds__(256)
void lnkv_ctx(const u16* __restrict__ qkv,
              const float* __restrict__ kw, const float* __restrict__ kb,
              const float* __restrict__ vw, const float* __restrict__ vb,
              float* __restrict__ ctxP) {
    const int bh = blockIdx.x, b = bh >> 2, h = bh & 3;
    const int nc = blockIdx.y;
    const int wv = threadIdx.x >> 6, l = threadIdx.x & 63;
    const int md = l & 15, qd = l >> 4;
    __shared__ __align__(16) u16 lk[128 * 72], lv[128 * 72];

    f4_t acc[8][2];
    #pragma unroll
    for (int i = 0; i < 8; ++i) { acc[i][0] = (f4_t){0,0,0,0}; acc[i][1] = (f4_t){0,0,0,0}; }

    for (int ss = 0; ss < 4; ++ss) {
        const int n0 = nc * 256 + ss * 64;
        for (int r = wv; r < 64; r += 4) {
            long base = ((long)b * N_ + n0 + r) * 1536 + h * 128;
            {   // k at column block 512
                float x0 = bf2f(qkv[base + 512 + l]), x1 = bf2f(qkv[base + 512 + 64 + l]);
                float s = x0 + x1, q = x0 * x0 + x1 * x1;
                #pragma unroll
                for (int o = 32; o >= 1; o >>= 1) { s += __shfl_xor(s, o, 64); q += __shfl_xor(q, o, 64); }
                float mu = s * (1.f / 128.f), var = q * (1.f / 128.f) - mu * mu;
                float rs = rsqrtf(var + EPS_);
                lk[l * 72 + r]        = f2bf((x0 - mu) * rs * kw[l] + kb[l]);
                lk[(l + 64) * 72 + r] = f2bf((x1 - mu) * rs * kw[l + 64] + kb[l + 64]);
            }
            {   // v at column block 1024
                float x0 = bf2f(qkv[base + 1024 + l]), x1 = bf2f(qkv[base + 1024 + 64 + l]);
                float s = x0 + x1, q = x0 * x0 + x1 * x1;
                #pragma unroll
                for (int o = 32; o >= 1; o >>= 1) { s += __shfl_xor(s, o, 64); q += __shfl_xor(q, o, 64); }
                float mu = s * (1.f / 128.f), var = q * (1.f / 128.f) - mu * mu;
                float rs = rsqrtf(var + EPS_);
                lv[l * 72 + r]        = f2bf((x0 - mu) * rs * vw[l] + vb[l]);
                lv[(l + 64) * 72 + r] = f2bf((x1 - mu) * rs * vw[l + 64] + vb[l + 64]);
            }
        }
        __syncthreads();
        // MFMA: A = k^T (m=d), B = v^T (n=e); K-dim = n rows, two 32-slices.
        // wave wv owns e-range [wv*32, wv*32+32).
        #pragma unroll
        for (int ks = 0; ks < 2; ++ks) {
            const int ko = ks * 32 + qd * 8;
            bfrag_t bf0 = *(const bfrag_t*)&lv[(wv * 32 + md) * 72 + ko];
            bfrag_t bf1 = *(const bfrag_t*)&lv[(wv * 32 + 16 + md) * 72 + ko];
            #pragma unroll
            for (int db = 0; db < 8; ++db) {
                bfrag_t af = *(const bfrag_t*)&lk[(db * 16 + md) * 72 + ko];
                acc[db][0] = __builtin_amdgcn_mfma_f32_16x16x32_bf16(af, bf0, acc[db][0], 0, 0, 0);
                acc[db][1] = __builtin_amdgcn_mfma_f32_16x16x32_bf16(af, bf1, acc[db][1], 0, 0, 0);
            }
        }
        __syncthreads();
    }
    // store partial: C/D layout col=lane&15 (e), row=(lane>>4)*4+reg (d)
    float* o = ctxP + ((long)bh * 32 + nc) * 16384;
    #pragma unroll
    for (int db = 0; db < 8; ++db)
        #pragma unroll
        for (int rr = 0; rr < 4; ++rr) {
            const int d = db * 16 + qd * 4 + rr;
            #pragma unroll
            for (int eb = 0; eb < 2; ++eb)
                o[d * 128 + wv * 32 + eb * 16 + md] = acc[db][eb][rr];
        }
}

// ------- ctx reduce: ctxN[bh][d][e] = SCALE * sum_p ctxP[bh][p][d][e] -> bf16 ---
__global__ void ctxfin(const float* __restrict__ ctxP, u16* __restrict__ ctxN) {
    int idx = blockIdx.x * 256 + threadIdx.x;
    if (idx >= 16 * 16384) return;
    int bh = idx >> 14, r = idx & 16383;
    const float* p = ctxP + (long)bh * 524288 + r;
    float s = 0.f;
    #pragma unroll
    for (int q = 0; q < 32; q++) s += p[q * 16384];
    ctxN[idx] = f2bf(s * SCALE_);
}

// ---------------- legacy 128x128 GEMM: W_eff only ------------------------------
// MODE 0: bf16 store
template<int MODE, int KTOT, int ZDIV>
__global__ __launch_bounds__(256)
void gemm_bt(const u16* __restrict__ A, int lda, int64_t aZ1, int64_t aZ2,
             const u16* __restrict__ Bt, int ldb, int64_t bZ1, int64_t bZ2,
             void* __restrict__ outv, int ldo, int64_t oZ1, int64_t oZ2,
             const float* __restrict__ bias, const float* __restrict__ resid, int ldr) {
    __shared__ __align__(16) u16 sA[128 * 32];
    __shared__ __align__(16) u16 sB[128 * 32];
    const int z = blockIdx.z;
    const int z1 = z / ZDIV, z2 = z % ZDIV;
    A  += z1 * aZ1 + z2 * aZ2;
    Bt += z1 * bZ1 + z2 * bZ2;
    const int64_t ooff = z1 * oZ1 + z2 * oZ2;
    const int m0 = blockIdx.x * 128, n0 = blockIdx.y * 128;
    const int tid = threadIdx.x, wave = tid >> 6, lane = tid & 63;
    const int wr = wave >> 1, wc = wave & 1;

    f4_t acc[4][4];
    #pragma unroll
    for (int i = 0; i < 4; i++)
        #pragma unroll
        for (int j = 0; j < 4; j++) acc[i][j] = (f4_t){0.f, 0.f, 0.f, 0.f};

    const int c0 = wave * 64 + lane, c1 = 256 + wave * 64 + lane;
    const int r0 = c0 >> 2, e0 = (c0 & 3) * 8;
    const int r1 = c1 >> 2, e1 = (c1 & 3) * 8;
    const u16* a0 = A + (int64_t)(m0 + r0) * lda + e0;
    const u16* a1 = A + (int64_t)(m0 + r1) * lda + e1;
    const u16* b0 = Bt + (int64_t)(n0 + r0) * ldb + e0;
    const u16* b1 = Bt + (int64_t)(n0 + r1) * ldb + e1;
    u16* lA0 = &sA[wave * 512];        u16* lA1 = &sA[2048 + wave * 512];
    u16* lB0 = &sB[wave * 512];        u16* lB1 = &sB[2048 + wave * 512];

    const int qd = lane >> 4, md = lane & 15;
    int aoff[4], boff[4];
    #pragma unroll
    for (int i = 0; i < 4; i++) {
        aoff[i] = (wr * 64 + i * 16 + md) * 32 + qd * 8;
        boff[i] = (wc * 64 + i * 16 + md) * 32 + qd * 8;
    }

    #pragma unroll 4
    for (int kt = 0; kt < KTOT; kt += 32) {
        __syncthreads();
        gld16(lA0, a0 + kt);  gld16(lA1, a1 + kt);
        gld16(lB0, b0 + kt);  gld16(lB1, b1 + kt);
        __syncthreads();
        bfrag_t af[4], bf[4];
        #pragma unroll
        for (int i = 0; i < 4; i++) af[i] = *(const bfrag_t*)&sA[aoff[i]];
        #pragma unroll
        for (int i = 0; i < 4; i++) bf[i] = *(const bfrag_t*)&sB[boff[i]];
        #pragma unroll
        for (int mi = 0; mi < 4; mi++)
            #pragma unroll
            for (int ni = 0; ni < 4; ni++)
                acc[mi][ni] = __builtin_amdgcn_mfma_f32_16x16x32_bf16(
                    af[mi], bf[ni], acc[mi][ni], 0, 0, 0);
    }

    #pragma unroll
    for (int mi = 0; mi < 4; mi++) {
        #pragma unroll
        for (int r = 0; r < 4; r++) {
            int m = m0 + wr * 64 + mi * 16 + qd * 4 + r;
            int64_t rowo = ooff + (int64_t)m * ldo;
            #pragma unroll
            for (int ni = 0; ni < 4; ni++) {
                int n = n0 + wc * 64 + ni * 16 + md;
                float v = acc[mi][ni][r];
                if (MODE == 0)
                    ((u16*)outv)[rowo + n] = f2bf_fast(v);
                else
                    ((float*)outv)[rowo + n] = v;
            }
        }
    }
}

// ---------------- 256x256 BK=64 8-wave counted-vmcnt GEMM (batched) ------------
// MODE 1: bf16 + bias (qkv)  MODE 2: bf16 + bias + gelu (mlp1)  -> UNSWAPPED
// MODE 3: f32 + bias + resid (proj-fused, mlp2)                 -> SWAPPED
#define LD_(p)      (*(const bfrag_t*)(p))
#define FENCE_      asm volatile("" ::: "memory")
#define BAR_        do { FENCE_; __builtin_amdgcn_s_barrier(); FENCE_; } while (0)
#define WVM4_       asm volatile("s_waitcnt vmcnt(4)" ::: "memory")
#define WVM0_       asm volatile("s_waitcnt vmcnt(0)" ::: "memory")
#define MFMA_(va, vb, c) c = __builtin_amdgcn_mfma_f32_16x16x32_bf16(va, vb, c, 0, 0, 0)
#define MM16U_(I0) do { __builtin_amdgcn_s_setprio(1); \
  MFMA_(a0,b0,acc[(I0)+0][0]); MFMA_(a0,b1,acc[(I0)+0][1]); MFMA_(a0,b2,acc[(I0)+0][2]); MFMA_(a0,b3,acc[(I0)+0][3]); \
  MFMA_(a1,b0,acc[(I0)+1][0]); MFMA_(a1,b1,acc[(I0)+1][1]); MFMA_(a1,b2,acc[(I0)+1][2]); MFMA_(a1,b3,acc[(I0)+1][3]); \
  MFMA_(a2,b0,acc[(I0)+2][0]); MFMA_(a2,b1,acc[(I0)+2][1]); MFMA_(a2,b2,acc[(I0)+2][2]); MFMA_(a2,b3,acc[(I0)+2][3]); \
  MFMA_(a3,b0,acc[(I0)+3][0]); MFMA_(a3,b1,acc[(I0)+3][1]); MFMA_(a3,b2,acc[(I0)+3][2]); MFMA_(a3,b3,acc[(I0)+3][3]); \
  __builtin_amdgcn_s_setprio(0); } while (0)
#define MM16S_(I0) do { __builtin_amdgcn_s_setprio(1); \
  MFMA_(b0,a0,acc[(I0)+0][0]); MFMA_(b1,a0,acc[(I0)+0][1]); MFMA_(b2,a0,acc[(I0)+0][2]); MFMA_(b3,a0,acc[(I0)+0][3]); \
  MFMA_(b0,a1,acc[(I0)+1][0]); MFMA_(b1,a1,acc[(I0)+1][1]); MFMA_(b2,a1,acc[(I0)+1][2]); MFMA_(b3,a1,acc[(I0)+1][3]); \
  MFMA_(b0,a2,acc[(I0)+2][0]); MFMA_(b1,a2,acc[(I0)+2][1]); MFMA_(b2,a2,acc[(I0)+2][2]); MFMA_(b3,a2,acc[(I0)+2][3]); \
  MFMA_(b0,a3,acc[(I0)+3][0]); MFMA_(b1,a3,acc[(I0)+3][1]); MFMA_(b2,a3,acc[(I0)+3][2]); MFMA_(b3,a3,acc[(I0)+3][3]); \
  __builtin_amdgcn_s_setprio(0); } while (0)
#define MM16_(I0) do { if (MODE == 3) MM16S_(I0); else MM16U_(I0); } while (0)
#define STGA_(nb, kk, tt) do { \
  u16* d_ = lds + (nb) * 32768 + (kk) * 8192 + wid * 512; \
  const u16* s_ = aS + (int64_t)(tt) * 64 + (kk) * 32; \
  gld16(d_, s_); gld16(d_ + 4096, s_ + a128); } while (0)
#define STGB_(nb, kk, tt) do { \
  u16* d_ = lds + (nb) * 32768 + 16384 + (kk) * 8192 + wid * 512; \
  const u16* s_ = bS + (int64_t)(tt) * 64 + (kk) * 32; \
  gld16(d_, s_); gld16(d_ + 4096, s_ + b128); } while (0)

template<int MODE, int KTOT>
__global__ __launch_bounds__(512, 2)
void gemm256(const u16* __restrict__ A, int lda, int64_t aZ,
             const u16* __restrict__ Bt, int ldb, int64_t bZ,
             void* __restrict__ outv, int ldo, int64_t oZ,
             const float* __restrict__ bias, const float* __restrict__ resid, int ldr) {
    __shared__ __align__(16) u16 lds[65536];   // 128 KiB
    const int z = blockIdx.z;
    A += (int64_t)z * aZ;
    Bt += (int64_t)z * bZ;
    const int64_t ooff = (int64_t)z * oZ;      // resid shares out layout/stride
    // T1: XCD-chunked bijective block swizzle (gx multiple of 8 on all launches)
    const int gx = gridDim.x, gy = gridDim.y;
    const int lid = blockIdx.x + blockIdx.y * gx;
    int bx, by;
    if ((gx & 7) == 0) {
        const int j = lid >> 3;
        bx = (gx >> 3) * (lid & 7) + j / gy;
        by = j % gy;
    } else { bx = blockIdx.x; by = blockIdx.y; }
    const int m0 = bx * 256, n0 = by * 256;
    const int tid = threadIdx.x, wid = tid >> 6, lane = tid & 63;
    const int wr = wid >> 2, wc = wid & 3;      // 2x4 wave grid, 128x64 per wave
    const int md = lane & 15, qd = lane >> 4;

    f4_t acc[8][4];
    #pragma unroll
    for (int i = 0; i < 8; ++i)
        #pragma unroll
        for (int j = 0; j < 4; ++j) acc[i][j] = (f4_t){0.f, 0.f, 0.f, 0.f};

    // staging: per half-plane, thread handles chunks c = r*512+tid (r=0,1):
    // row = r*128 + tid>>2, cstore = tid&3; source chunk = cstore ^ ((row>>1)&3)
    const int srow = tid >> 2;
    const int scol = ((tid & 3) ^ ((tid >> 3) & 3)) * 8;    // u16 col within plane
    const u16* aS = A  + (int64_t)(m0 + srow) * lda + scol;
    const u16* bS = Bt + (int64_t)(n0 + srow) * ldb + scol;
    const int64_t a128 = (int64_t)lda * 128, b128 = (int64_t)ldb * 128;

    // ds_read side: frag row -> byte row*64 within plane; chunk qd stored at
    // position qd ^ ((row>>1)&3); (row>>1)&3 == (md>>1)&3
    const int xq = (qd ^ ((md >> 1) & 3)) * 16;   // byte offset within 64B row
    const int aRow = (wr * 128 + md) * 64;
    const int bRow = (wc * 64 + md) * 64;
    const char* ldsc = (const char*)lds;

    constexpr int NT = KTOT / 64;

    {   // prologue: tile 0 -> buf 0, order A0,B0,A1,B1; wait only the kk=0 planes
        STGA_(0, 0, 0); STGB_(0, 0, 0); STGA_(0, 1, 0); STGB_(0, 1, 0);
        WVM4_; BAR_;
    }

    #pragma unroll 2
    for (int t = 0; t < NT; ++t) {
        const int cur = t & 1, nb = cur ^ 1;
        const char* cA = ldsc + cur * 65536 + aRow;          // kk0 A plane
        const char* cB = ldsc + cur * 65536 + 32768 + bRow;  // kk0 B plane
        const bool st = (t + 1 < NT);
        bfrag_t a0, a1, a2, a3, b0, b1, b2, b3;

        // p0: kk0, m-frags 0..3 + all B(kk0); stage A-kk0 of t+1
        a0 = LD_(cA + xq);        a1 = LD_(cA + 1024 + xq);
        a2 = LD_(cA + 2048 + xq); a3 = LD_(cA + 3072 + xq);
        b0 = LD_(cB + xq);        b1 = LD_(cB + 1024 + xq);
        b2 = LD_(cB + 2048 + xq); b3 = LD_(cB + 3072 + xq);
        if (st) STGA_(nb, 0, t + 1);
        BAR_;
        MM16_(0);

        // p1: kk0, m-frags 4..7 (B held); stage B-kk0 of t+1
        a0 = LD_(cA + 4096 + xq); a1 = LD_(cA + 5120 + xq);
        a2 = LD_(cA + 6144 + xq); a3 = LD_(cA + 7168 + xq);
        if (st) STGB_(nb, 0, t + 1);
        BAR_;
        MM16_(4);

        // W1: kk=1 planes of tile t resident; newest 4 loads stay in flight
        if (st) { WVM4_; } else { WVM0_; }
        BAR_;

        // p2: kk1, m-frags 0..3 + all B(kk1); stage A-kk1 of t+1
        a0 = LD_(cA + 16384 + xq);        a1 = LD_(cA + 17408 + xq);
        a2 = LD_(cA + 18432 + xq);        a3 = LD_(cA + 19456 + xq);
        b0 = LD_(cB + 16384 + xq);        b1 = LD_(cB + 17408 + xq);
        b2 = LD_(cB + 18432 + xq);        b3 = LD_(cB + 19456 + xq);
        if (st) STGA_(nb, 1, t + 1);
        BAR_;
        MM16_(0);

        // p3: kk1, m-frags 4..7; stage B-kk1 of t+1
        a0 = LD_(cA + 20480 + xq); a1 = LD_(cA + 21504 + xq);
        a2 = LD_(cA + 22528 + xq); a3 = LD_(cA + 23552 + xq);
        if (st) STGB_(nb, 1, t + 1);
        BAR_;
        MM16_(4);

        // W2 (boundary): kk=0 planes of tile t+1 resident; kk=1 planes fly on
        if (st) { WVM4_; } else { WVM0_; }
        BAR_;
    }

    if (MODE == 3) {
        // swapped layout: per (i,j): row m = ..+i*16+md (fixed per lane),
        // cols n = ..+j*16+qd*4 + {0..3} consecutive -> vector f32x4 path.
        #pragma unroll
        for (int i = 0; i < 8; ++i) {
            const int m = m0 + wr * 128 + i * 16 + md;
            const int64_t rowo = ooff + (int64_t)m * ldo;
            #pragma unroll
            for (int j = 0; j < 4; ++j) {
                const int n = n0 + wc * 64 + j * 16 + qd * 4;
                f4_t v = acc[i][j];
                const f4_t bq = *(const f4_t*)&bias[n];
                v.x += bq.x; v.y += bq.y; v.z += bq.z; v.w += bq.w;
                const f4_t r4 = *(const f4_t*)&resid[ooff + (int64_t)m * ldr + n];
                v.x += r4.x; v.y += r4.y; v.z += r4.z; v.w += r4.w;
                *(f4_t*)&((float*)outv)[rowo + n] = v;
            }
        }
    } else {
        // unswapped layout (r3-measured): col = lane&15, row = (lane>>4)*4 + reg
        #pragma unroll
        for (int i = 0; i < 8; ++i) {
            #pragma unroll
            for (int rr = 0; rr < 4; ++rr) {
                const int m = m0 + wr * 128 + i * 16 + qd * 4 + rr;
                const int64_t rowo = ooff + (int64_t)m * ldo;
                #pragma unroll
                for (int j = 0; j < 4; ++j) {
                    const int n = n0 + wc * 64 + j * 16 + md;
                    float v = acc[i][j][rr];
                    v += bias[n];
                    if (MODE == 2) v = fast_gelu(v);
                    ((u16*)outv)[rowo + n] = f2bf_fast(v);
                }
            }
        }
    }
}

#undef LD_
#undef FENCE_
#undef BAR_
#undef WVM4_
#undef WVM0_
#undef MFMA_
#undef MM16U_
#undef MM16S_
#undef MM16_
#undef STGA_
#undef STGB_

// ------------------------------- launcher --------------------------------------
extern "C" void kernel_launch(void* const* d_in, const int* in_sizes, int n_in,
                              void* d_out, int out_size, void* d_ws, size_t ws_size,
                              hipStream_t stream) {
    const float* x      = (const float*)d_in[0];
    const float* n1w    = (const float*)d_in[1];
    const float* n1b    = (const float*)d_in[2];
    const float* qkv_w  = (const float*)d_in[3];
    const float* qkv_b  = (const float*)d_in[4];
    const float* lnk_w  = (const float*)d_in[5];
    const float* lnk_b  = (const float*)d_in[6];
    const float* lnv_w  = (const float*)d_in[7];
    const float* lnv_b  = (const float*)d_in[8];
    const float* proj_w = (const float*)d_in[9];
    const float* proj_b = (const float*)d_in[10];
    const float* n2w    = (const float*)d_in[11];
    const float* n2b    = (const float*)d_in[12];
    const float* w1     = (const float*)d_in[13];
    const float* b1     = (const float*)d_in[14];
    const float* w2     = (const float*)d_in[15];
    const float* b2     = (const float*)d_in[16];
    float* out = (float*)d_out;                 // x1 lives here, then final

    // workspace layout (~209.2 MB)
    char* ws = (char*)d_ws;
    u16*  qkvWT = (u16*)(ws + 0);               // [1536,512] bf16   1.5 MB
    u16*  projT = (u16*)(ws + 1572864);         // [512,512]         0.5 MB
    u16*  w1T   = (u16*)(ws + 2097152);         // [2048,512]        2 MB
    u16*  w2T   = (u16*)(ws + 4194304);         // [512,2048]        2 MB
    u16*  ctxN  = (u16*)(ws + 7340032);         // [16,128,128] bf16 0.5 MB
    u16*  bufA  = (u16*)(ws + 7864320);         // xn/ctxP/h scratch 32 MB
    u16*  qkv   = (u16*)(ws + 41418752);        // [32768,1536] bf16 96 MB
    u16*  hid   = (u16*)(ws + 41418752);        // overlays qkv (dead by then)
    u16*  wqT   = (u16*)(ws + 142082048);       // [4][512,512] bf16 W_eff^T 2 MB
    // overlay inside bufA (xn dead after qkv-gemm; h written after proj-fused):
    float* ctxP = (float*)(ws + 7864320);       // [16,32,128,128] f32 partials 32 MB

    dim3 blk(256);
    dim3 blk5(512);

    // weights -> bf16 transposed [N,K] (LDS-tiled, coalesced both sides)
    wtrans<<<dim3((512 / 64) * (1536 / 64)), blk, 0, stream>>>(qkv_w, qkvWT, 512, 1536);
    wtrans<<<dim3((512 / 64) * (512 / 64)),  blk, 0, stream>>>(proj_w, projT, 512, 512);
    wtrans<<<dim3((512 / 64) * (2048 / 64)), blk, 0, stream>>>(w1, w1T, 512, 2048);
    wtrans<<<dim3((2048 / 64) * (512 / 64)), blk, 0, stream>>>(w2, w2T, 2048, 512);

    // LN1: x -> xn (bufA)
    ln_rows<<<dim3(M_), blk, 0, stream>>>(x, n1w, n1b, bufA);

    // qkv = xn @ qkv_w + qkv_b   [32768,1536] bf16
    gemm256<1, 512><<<dim3(M_ / 256, 1536 / 256, 1), blk5, 0, stream>>>(
        bufA, 512, 0, qkvWT, 512, 0, (void*)qkv, 1536, 0, qkv_b, nullptr, 0);

    // fused LN(k),LN(v) + ctx partials (kT/vT intermediates eliminated)
    lnkv_ctx<<<dim3(B_ * H_, 32), blk, 0, stream>>>(
        qkv, lnk_w, lnk_b, lnv_w, lnv_b, ctxP);
    // reduce 32 partials + SCALE -> ctxN[bh][d][e] bf16
    ctxfin<<<dim3(16 * 16384 / 256), blk, 0, stream>>>(ctxP, ctxN);

    // W_eff^T[b][j, h*128+d] = sum_e proj_w[h*128+e, j] * ctx_scaled[bh][d,e]
    gemm_bt<0, 128, 4><<<dim3(4, 1, 16), blk, 0, stream>>>(
        projT, 512, 0, 128,  ctxN, 128, 65536, 16384,
        (void*)wqT, 512, 262144, 128,  nullptr, nullptr, 0);

    // x1 = q @ W_eff + proj_b + x  -> d_out (fp32)   [attn+proj fused, z=batch]
    gemm256<3, 512><<<dim3(N_ / 256, 512 / 256, B_), blk5, 0, stream>>>(
        qkv, 1536, (int64_t)N_ * 1536,  wqT, 512, 262144,
        (void*)out, 512, (int64_t)N_ * 512,  proj_b, x, 512);

    // LN2: x1 -> h (bufA)
    ln_rows<<<dim3(M_), blk, 0, stream>>>(out, n2w, n2b, bufA);

    // hid = gelu(h @ w1 + b1)  [32768,2048] bf16
    gemm256<2, 512><<<dim3(M_ / 256, HID_ / 256, 1), blk5, 0, stream>>>(
        bufA, 512, 0, w1T, 512, 0, (void*)hid, HID_, 0, b1, nullptr, 0);

    // out = x1 + hid @ w2 + b2   (resid = d_out read-before-write per thread)
    gemm256<3, 2048><<<dim3(M_ / 256, 512 / 256, 1), blk5, 0, stream>>>(
        hid, HID_, 0, w2T, HID_, 0, (void*)out, 512, 0, b2, out, 512);
}

// Round 6
// 538.640 us; speedup vs baseline: 1.0208x; 1.0208x over previous
//
#include <hip/hip_runtime.h>
#include <stdint.h>

// GalerkinBlock: x -> LN1 -> qkv -> [fused LN(k),LN(v)+ctx=K^T V] -> [attn+proj
//   fused: x1 = q @ (ctx_scaled @ proj_w) + proj_b + x] -> LN2 -> mlp -> x1+mlp
// B=4 N=8192 C=512 H=4 D=128 HID=2048. All GEMMs bf16 MFMA (16x16x32), fp32 accum.
// Big GEMMs: 256x256 tile, BK=64, 8 waves, dbuf LDS (128 KiB), 4-phase interleave.
// r6 schedule: ALL 4 half-planes of tile t+1 issued at p0/p1 (A at p0, B at p1);
// FIFO-derived counted waits: W1=vmcnt(8) (drains prev B1, ~free), W2=vmcnt(2)
// (A0/A1/B0 aged 3-4 phases ~1000cy >= HBM latency). Loads never drain to 0 in
// steady state (T4). XOR swizzle (T2), setprio (T5), XCD swizzle (T1).
// MODE 3 swapped MFMA + vector epilogue (r4 win); MODES 1/2 unswapped (r4 lesson).

#define B_    4
#define N_    8192
#define C_    512
#define H_    4
#define D_    128
#define HID_  2048
#define M_    (B_*N_)          // 32768 rows
#define EPS_  1e-5f
#define SCALE_ 0.08838834764831845f   // D^-0.5

typedef unsigned short u16;
typedef unsigned int u32;
typedef __attribute__((ext_vector_type(8))) __bf16 bfrag_t;  // MFMA A/B frag (4 VGPRs)
typedef __attribute__((ext_vector_type(4))) float  f4_t;     // MFMA C/D frag
typedef __attribute__((ext_vector_type(2))) u32    u32x2;

__device__ __forceinline__ float bf2f(u16 a) {
    u32 u = ((u32)a) << 16; float f;
    __builtin_memcpy(&f, &u, 4); return f;
}
__device__ __forceinline__ u16 f2bf(float f) {                // RNE (cold paths)
    u32 u; __builtin_memcpy(&u, &f, 4);
    u += 0x7FFFu + ((u >> 16) & 1u);
    return (u16)(u >> 16);
}
__device__ __forceinline__ u16 f2bf_fast(float f) {           // round-half-up (hot epilogue)
    u32 u; __builtin_memcpy(&u, &f, 4);
    return (u16)((u + 0x8000u) >> 16);
}

// branch-free tanh-approx GELU
__device__ __forceinline__ float fast_gelu(float x) {
    const float kA = 2.3022084f;   // 2*0.7978845608*log2(e)
    const float kB = 0.1029435f;   // kA*0.044715
    float x2 = x * x;
    float e1 = __builtin_amdgcn_exp2f(x * (kB * x2 + kA));
    return x - x * __builtin_amdgcn_rcpf(e1 + 1.0f);
}

// async 16B global->LDS (lands at wave-uniform ldsbase + lane*16)
__device__ __forceinline__ void gld16(u16* lds, const u16* g) {
    void* gp = const_cast<u16*>(g);
    __builtin_amdgcn_global_load_lds((__attribute__((address_space(1))) void*)gp,
                                     (__attribute__((address_space(3))) void*)lds,
                                     16, 0, 0);
}

// ------- weight transpose+convert: fp32 [K,Ncols] -> bf16 [Ncols,K], LDS-tiled --
__global__ __launch_bounds__(256)
void wtrans(const float* __restrict__ in, u16* __restrict__ out,
            int K, int Ncols) {
    const int nb = Ncols >> 6;
    const int k0 = (blockIdx.x / nb) << 6, n0 = (blockIdx.x % nb) << 6;
    __shared__ u16 tile[64][65];
    const int tx = threadIdx.x & 63, ty = threadIdx.x >> 6;
    #pragma unroll
    for (int r = 0; r < 16; ++r) {
        int k = ty + r * 4;
        tile[k][tx] = f2bf(in[(long)(k0 + k) * Ncols + n0 + tx]);
    }
    __syncthreads();
    #pragma unroll
    for (int r = 0; r < 16; ++r) {
        int n = ty + r * 4;
        out[(long)(n0 + n) * K + k0 + tx] = tile[tx][n];
    }
}

// ---------------- row LayerNorm over 512 fp32 -> bf16 --------------------------
__global__ __launch_bounds__(256)
void ln_rows(const float* __restrict__ in, const float* __restrict__ w,
             const float* __restrict__ b, u16* __restrict__ out) {
    long row = blockIdx.x;
    int t = threadIdx.x;
    const float* p = in + row * 512;
    float v0 = p[t], v1 = p[t + 256];
    float s = v0 + v1, q = v0 * v0 + v1 * v1;
    #pragma unroll
    for (int o = 32; o >= 1; o >>= 1) { s += __shfl_xor(s, o, 64); q += __shfl_xor(q, o, 64); }
    __shared__ float sh[8];
    int wv = t >> 6, l = t & 63;
    if (l == 0) { sh[wv] = s; sh[4 + wv] = q; }
    __syncthreads();
    s = sh[0] + sh[1] + sh[2] + sh[3];
    q = sh[4] + sh[5] + sh[6] + sh[7];
    float mu = s * (1.f / 512.f);
    float var = q * (1.f / 512.f) - mu * mu;
    float rs = rsqrtf(var + EPS_);
    out[row * 512 + t]       = f2bf((v0 - mu) * rs * w[t] + b[t]);
    out[row * 512 + t + 256] = f2bf((v1 - mu) * rs * w[t + 256] + b[t + 256]);
}

// ------- fused LN(k),LN(v) + ctx partial: ctxP[bh][nc] += K_ln^T V_ln ----------
// grid (16 bh, 64 n-chunks of 128). Per sub-slice of 64 rows: LN k,v into
// transposed LDS tiles [128 d][72 n-stride], then MFMA outer-product accumulate
// 128x128. 2 sub-slices -> f32 partial store.
__global__ __launch_bounds__(256)
void lnkv_ctx(const u16* __restrict__ qkv,
              const float* __restrict__ kw, const float* __restrict__ kb,
              const float* __restrict__ vw, const float* __restrict__ vb,
              float* __restrict__ ctxP) {
    const int bh = blockIdx.x, b = bh >> 2, h = bh & 3;
    const int nc = blockIdx.y;
    const int wv = threadIdx.x >> 6, l = threadIdx.x & 63;
    const int md = l & 15, qd = l >> 4;
    __shared__ __align__(16) u16 lk[128 * 72], lv[128 * 72];

    f4_t acc[8][2];
    #pragma unroll
    for (int i = 0; i < 8; ++i) { acc[i][0] = (f4_t){0,0,0,0}; acc[i][1] = (f4_t){0,0,0,0}; }

    for (int ss = 0; ss < 2; ++ss) {
        const int n0 = nc * 128 + ss * 64;
        for (int r = wv; r < 64; r += 4) {
            long base = ((long)b * N_ + n0 + r) * 1536 + h * 128;
            {   // k at column block 512
                float x0 = bf2f(qkv[base + 512 + l]), x1 = bf2f(qkv[base + 512 + 64 + l]);
                float s = x0 + x1, q = x0 * x0 + x1 * x1;
                #pragma unroll
                for (int o = 32; o >= 1; o >>= 1) { s += __shfl_xor(s, o, 64); q += __shfl_xor(q, o, 64); }
                float mu = s * (1.f / 128.f), var = q * (1.f / 128.f) - mu * mu;
                float rs = rsqrtf(var + EPS_);
                lk[l * 72 + r]        = f2bf((x0 - mu) * rs * kw[l] + kb[l]);
                lk[(l + 64) * 72 + r] = f2bf((x1 - mu) * rs * kw[l + 64] + kb[l + 64]);
            }
            {   // v at column block 1024
                float x0 = bf2f(qkv[base + 1024 + l]), x1 = bf2f(qkv[base + 1024 + 64 + l]);
                float s = x0 + x1, q = x0 * x0 + x1 * x1;
                #pragma unroll
                for (int o = 32; o >= 1; o >>= 1) { s += __shfl_xor(s, o, 64); q += __shfl_xor(q, o, 64); }
                float mu = s * (1.f / 128.f), var = q * (1.f / 128.f) - mu * mu;
                float rs = rsqrtf(var + EPS_);
                lv[l * 72 + r]        = f2bf((x0 - mu) * rs * vw[l] + vb[l]);
                lv[(l + 64) * 72 + r] = f2bf((x1 - mu) * rs * vw[l + 64] + vb[l + 64]);
            }
        }
        __syncthreads();
        // MFMA: A = k^T (m=d), B = v^T (n=e); K-dim = n rows, two 32-slices.
        #pragma unroll
        for (int ks = 0; ks < 2; ++ks) {
            const int ko = ks * 32 + qd * 8;
            bfrag_t bf0 = *(const bfrag_t*)&lv[(wv * 32 + md) * 72 + ko];
            bfrag_t bf1 = *(const bfrag_t*)&lv[(wv * 32 + 16 + md) * 72 + ko];
            #pragma unroll
            for (int db = 0; db < 8; ++db) {
                bfrag_t af = *(const bfrag_t*)&lk[(db * 16 + md) * 72 + ko];
                acc[db][0] = __builtin_amdgcn_mfma_f32_16x16x32_bf16(af, bf0, acc[db][0], 0, 0, 0);
                acc[db][1] = __builtin_amdgcn_mfma_f32_16x16x32_bf16(af, bf1, acc[db][1], 0, 0, 0);
            }
        }
        __syncthreads();
    }
    // store partial: C/D layout col=lane&15 (e), row=(lane>>4)*4+reg (d)
    float* o = ctxP + ((long)bh * 64 + nc) * 16384;
    #pragma unroll
    for (int db = 0; db < 8; ++db)
        #pragma unroll
        for (int rr = 0; rr < 4; ++rr) {
            const int d = db * 16 + qd * 4 + rr;
            #pragma unroll
            for (int eb = 0; eb < 2; ++eb)
                o[d * 128 + wv * 32 + eb * 16 + md] = acc[db][eb][rr];
        }
}

// ------- ctx reduce: ctxN[bh][d][e] = SCALE * sum_p ctxP[bh][p][d][e] -> bf16 ---
__global__ void ctxfin(const float* __restrict__ ctxP, u16* __restrict__ ctxN) {
    int idx = blockIdx.x * 256 + threadIdx.x;
    if (idx >= 16 * 16384) return;
    int bh = idx >> 14, r = idx & 16383;
    const float* p = ctxP + (long)bh * 1048576 + r;
    float s = 0.f;
    #pragma unroll
    for (int q = 0; q < 64; q++) s += p[q * 16384];
    ctxN[idx] = f2bf(s * SCALE_);
}

// ---------------- legacy 128x128 GEMM: W_eff only ------------------------------
template<int MODE, int KTOT, int ZDIV>
__global__ __launch_bounds__(256)
void gemm_bt(const u16* __restrict__ A, int lda, int64_t aZ1, int64_t aZ2,
             const u16* __restrict__ Bt, int ldb, int64_t bZ1, int64_t bZ2,
             void* __restrict__ outv, int ldo, int64_t oZ1, int64_t oZ2,
             const float* __restrict__ bias, const float* __restrict__ resid, int ldr) {
    __shared__ __align__(16) u16 sA[128 * 32];
    __shared__ __align__(16) u16 sB[128 * 32];
    const int z = blockIdx.z;
    const int z1 = z / ZDIV, z2 = z % ZDIV;
    A  += z1 * aZ1 + z2 * aZ2;
    Bt += z1 * bZ1 + z2 * bZ2;
    const int64_t ooff = z1 * oZ1 + z2 * oZ2;
    const int m0 = blockIdx.x * 128, n0 = blockIdx.y * 128;
    const int tid = threadIdx.x, wave = tid >> 6, lane = tid & 63;
    const int wr = wave >> 1, wc = wave & 1;

    f4_t acc[4][4];
    #pragma unroll
    for (int i = 0; i < 4; i++)
        #pragma unroll
        for (int j = 0; j < 4; j++) acc[i][j] = (f4_t){0.f, 0.f, 0.f, 0.f};

    const int c0 = wave * 64 + lane, c1 = 256 + wave * 64 + lane;
    const int r0 = c0 >> 2, e0 = (c0 & 3) * 8;
    const int r1 = c1 >> 2, e1 = (c1 & 3) * 8;
    const u16* a0 = A + (int64_t)(m0 + r0) * lda + e0;
    const u16* a1 = A + (int64_t)(m0 + r1) * lda + e1;
    const u16* b0 = Bt + (int64_t)(n0 + r0) * ldb + e0;
    const u16* b1 = Bt + (int64_t)(n0 + r1) * ldb + e1;
    u16* lA0 = &sA[wave * 512];        u16* lA1 = &sA[2048 + wave * 512];
    u16* lB0 = &sB[wave * 512];        u16* lB1 = &sB[2048 + wave * 512];

    const int qd = lane >> 4, md = lane & 15;
    int aoff[4], boff[4];
    #pragma unroll
    for (int i = 0; i < 4; i++) {
        aoff[i] = (wr * 64 + i * 16 + md) * 32 + qd * 8;
        boff[i] = (wc * 64 + i * 16 + md) * 32 + qd * 8;
    }

    #pragma unroll 4
    for (int kt = 0; kt < KTOT; kt += 32) {
        __syncthreads();
        gld16(lA0, a0 + kt);  gld16(lA1, a1 + kt);
        gld16(lB0, b0 + kt);  gld16(lB1, b1 + kt);
        __syncthreads();
        bfrag_t af[4], bf[4];
        #pragma unroll
        for (int i = 0; i < 4; i++) af[i] = *(const bfrag_t*)&sA[aoff[i]];
        #pragma unroll
        for (int i = 0; i < 4; i++) bf[i] = *(const bfrag_t*)&sB[boff[i]];
        #pragma unroll
        for (int mi = 0; mi < 4; mi++)
            #pragma unroll
            for (int ni = 0; ni < 4; ni++)
                acc[mi][ni] = __builtin_amdgcn_mfma_f32_16x16x32_bf16(
                    af[mi], bf[ni], acc[mi][ni], 0, 0, 0);
    }

    #pragma unroll
    for (int mi = 0; mi < 4; mi++) {
        #pragma unroll
        for (int r = 0; r < 4; r++) {
            int m = m0 + wr * 64 + mi * 16 + qd * 4 + r;
            int64_t rowo = ooff + (int64_t)m * ldo;
            #pragma unroll
            for (int ni = 0; ni < 4; ni++) {
                int n = n0 + wc * 64 + ni * 16 + md;
                float v = acc[mi][ni][r];
                if (MODE == 0)
                    ((u16*)outv)[rowo + n] = f2bf_fast(v);
                else
                    ((float*)outv)[rowo + n] = v;
            }
        }
    }
}

// ---------------- 256x256 BK=64 8-wave counted-vmcnt GEMM (batched) ------------
// MODE 1: bf16 + bias (qkv)  MODE 2: bf16 + bias + gelu (mlp1)  -> UNSWAPPED
// MODE 3: f32 + bias + resid (proj-fused, mlp2)                 -> SWAPPED
#define LD_(p)      (*(const bfrag_t*)(p))
#define FENCE_      asm volatile("" ::: "memory")
#define BAR_        do { FENCE_; __builtin_amdgcn_s_barrier(); FENCE_; } while (0)
#define WVM8_       asm volatile("s_waitcnt vmcnt(8)" ::: "memory")
#define WVM2_       asm volatile("s_waitcnt vmcnt(2)" ::: "memory")
#define WVM0_       asm volatile("s_waitcnt vmcnt(0)" ::: "memory")
#define MFMA_(va, vb, c) c = __builtin_amdgcn_mfma_f32_16x16x32_bf16(va, vb, c, 0, 0, 0)
#define MM16U_(I0) do { __builtin_amdgcn_s_setprio(1); \
  MFMA_(a0,b0,acc[(I0)+0][0]); MFMA_(a0,b1,acc[(I0)+0][1]); MFMA_(a0,b2,acc[(I0)+0][2]); MFMA_(a0,b3,acc[(I0)+0][3]); \
  MFMA_(a1,b0,acc[(I0)+1][0]); MFMA_(a1,b1,acc[(I0)+1][1]); MFMA_(a1,b2,acc[(I0)+1][2]); MFMA_(a1,b3,acc[(I0)+1][3]); \
  MFMA_(a2,b0,acc[(I0)+2][0]); MFMA_(a2,b1,acc[(I0)+2][1]); MFMA_(a2,b2,acc[(I0)+2][2]); MFMA_(a2,b3,acc[(I0)+2][3]); \
  MFMA_(a3,b0,acc[(I0)+3][0]); MFMA_(a3,b1,acc[(I0)+3][1]); MFMA_(a3,b2,acc[(I0)+3][2]); MFMA_(a3,b3,acc[(I0)+3][3]); \
  __builtin_amdgcn_s_setprio(0); } while (0)
#define MM16S_(I0) do { __builtin_amdgcn_s_setprio(1); \
  MFMA_(b0,a0,acc[(I0)+0][0]); MFMA_(b1,a0,acc[(I0)+0][1]); MFMA_(b2,a0,acc[(I0)+0][2]); MFMA_(b3,a0,acc[(I0)+0][3]); \
  MFMA_(b0,a1,acc[(I0)+1][0]); MFMA_(b1,a1,acc[(I0)+1][1]); MFMA_(b2,a1,acc[(I0)+1][2]); MFMA_(b3,a1,acc[(I0)+1][3]); \
  MFMA_(b0,a2,acc[(I0)+2][0]); MFMA_(b1,a2,acc[(I0)+2][1]); MFMA_(b2,a2,acc[(I0)+2][2]); MFMA_(b3,a2,acc[(I0)+2][3]); \
  MFMA_(b0,a3,acc[(I0)+3][0]); MFMA_(b1,a3,acc[(I0)+3][1]); MFMA_(b2,a3,acc[(I0)+3][2]); MFMA_(b3,a3,acc[(I0)+3][3]); \
  __builtin_amdgcn_s_setprio(0); } while (0)
#define MM16_(I0) do { if (MODE == 3) MM16S_(I0); else MM16U_(I0); } while (0)
#define STGA_(nb, kk, tt) do { \
  u16* d_ = lds + (nb) * 32768 + (kk) * 8192 + wid * 512; \
  const u16* s_ = aS + (int64_t)(tt) * 64 + (kk) * 32; \
  gld16(d_, s_); gld16(d_ + 4096, s_ + a128); } while (0)
#define STGB_(nb, kk, tt) do { \
  u16* d_ = lds + (nb) * 32768 + 16384 + (kk) * 8192 + wid * 512; \
  const u16* s_ = bS + (int64_t)(tt) * 64 + (kk) * 32; \
  gld16(d_, s_); gld16(d_ + 4096, s_ + b128); } while (0)

template<int MODE, int KTOT>
__global__ __launch_bounds__(512, 2)
void gemm256(const u16* __restrict__ A, int lda, int64_t aZ,
             const u16* __restrict__ Bt, int ldb, int64_t bZ,
             void* __restrict__ outv, int ldo, int64_t oZ,
             const float* __restrict__ bias, const float* __restrict__ resid, int ldr) {
    __shared__ __align__(16) u16 lds[65536];   // 128 KiB
    const int z = blockIdx.z;
    A += (int64_t)z * aZ;
    Bt += (int64_t)z * bZ;
    const int64_t ooff = (int64_t)z * oZ;      // resid shares out layout/stride
    // T1: XCD-chunked bijective block swizzle (gx multiple of 8 on all launches)
    const int gx = gridDim.x, gy = gridDim.y;
    const int lid = blockIdx.x + blockIdx.y * gx;
    int bx, by;
    if ((gx & 7) == 0) {
        const int j = lid >> 3;
        bx = (gx >> 3) * (lid & 7) + j / gy;
        by = j % gy;
    } else { bx = blockIdx.x; by = blockIdx.y; }
    const int m0 = bx * 256, n0 = by * 256;
    const int tid = threadIdx.x, wid = tid >> 6, lane = tid & 63;
    const int wr = wid >> 2, wc = wid & 3;      // 2x4 wave grid, 128x64 per wave
    const int md = lane & 15, qd = lane >> 4;

    f4_t acc[8][4];
    #pragma unroll
    for (int i = 0; i < 8; ++i)
        #pragma unroll
        for (int j = 0; j < 4; ++j) acc[i][j] = (f4_t){0.f, 0.f, 0.f, 0.f};

    // staging: per half-plane, thread handles chunks c = r*512+tid (r=0,1):
    // row = r*128 + tid>>2, cstore = tid&3; source chunk = cstore ^ ((row>>1)&3)
    const int srow = tid >> 2;
    const int scol = ((tid & 3) ^ ((tid >> 3) & 3)) * 8;    // u16 col within plane
    const u16* aS = A  + (int64_t)(m0 + srow) * lda + scol;
    const u16* bS = Bt + (int64_t)(n0 + srow) * ldb + scol;
    const int64_t a128 = (int64_t)lda * 128, b128 = (int64_t)ldb * 128;

    // ds_read side: frag row -> byte row*64 within plane; chunk qd stored at
    // position qd ^ ((row>>1)&3); (row>>1)&3 == (md>>1)&3
    const int xq = (qd ^ ((md >> 1) & 3)) * 16;   // byte offset within 64B row
    const int aRow = (wr * 128 + md) * 64;
    const int bRow = (wc * 64 + md) * 64;
    const char* ldsc = (const char*)lds;

    constexpr int NT = KTOT / 64;

    {   // prologue: tile 0 -> buf 0 (all 4 planes), full drain
        STGA_(0, 0, 0); STGA_(0, 1, 0); STGB_(0, 0, 0); STGB_(0, 1, 0);
        WVM0_; BAR_;
    }

    // Steady-state FIFO (per-thread loads, oldest->newest at W2 of tile t):
    //   [A0 A0 A1 A1 B0 B0 B1 B1] of tile t+1  (A planes issued p0, B at p1)
    // W1(t) = vmcnt(8): drains B1(t) leftover (aged ~4 phases) - nearly free.
    // W2(t) = vmcnt(2): drains A0,A1,B0 of t+1 (aged 3-4 phases); B1(t+1) flies.
    #pragma unroll 2
    for (int t = 0; t < NT; ++t) {
        const int cur = t & 1, nb = cur ^ 1;
        const char* cA = ldsc + cur * 65536 + aRow;          // kk0 A plane
        const char* cB = ldsc + cur * 65536 + 32768 + bRow;  // kk0 B plane
        const bool st = (t + 1 < NT);
        bfrag_t a0, a1, a2, a3, b0, b1, b2, b3;

        // p0: kk0, m-frags 0..3 + all B(kk0); issue BOTH A planes of t+1
        a0 = LD_(cA + xq);        a1 = LD_(cA + 1024 + xq);
        a2 = LD_(cA + 2048 + xq); a3 = LD_(cA + 3072 + xq);
        b0 = LD_(cB + xq);        b1 = LD_(cB + 1024 + xq);
        b2 = LD_(cB + 2048 + xq); b3 = LD_(cB + 3072 + xq);
        if (st) { STGA_(nb, 0, t + 1); STGA_(nb, 1, t + 1); }
        BAR_;
        MM16_(0);

        // p1: kk0, m-frags 4..7 (B held); issue BOTH B planes of t+1
        a0 = LD_(cA + 4096 + xq); a1 = LD_(cA + 5120 + xq);
        a2 = LD_(cA + 6144 + xq); a3 = LD_(cA + 7168 + xq);
        if (st) { STGB_(nb, 0, t + 1); STGB_(nb, 1, t + 1); }
        BAR_;
        MM16_(4);

        // W1: kk=1 planes of tile t resident (only prev B1 may still fly)
        if (st) { WVM8_; } else { WVM0_; }
        BAR_;

        // p2: kk1, m-frags 0..3 + all B(kk1)
        a0 = LD_(cA + 16384 + xq);        a1 = LD_(cA + 17408 + xq);
        a2 = LD_(cA + 18432 + xq);        a3 = LD_(cA + 19456 + xq);
        b0 = LD_(cB + 16384 + xq);        b1 = LD_(cB + 17408 + xq);
        b2 = LD_(cB + 18432 + xq);        b3 = LD_(cB + 19456 + xq);
        BAR_;
        MM16_(0);

        // p3: kk1, m-frags 4..7
        a0 = LD_(cA + 20480 + xq); a1 = LD_(cA + 21504 + xq);
        a2 = LD_(cA + 22528 + xq); a3 = LD_(cA + 23552 + xq);
        BAR_;
        MM16_(4);

        // W2 (boundary): A0,A1,B0 of t+1 resident; B1 rides to next W1
        if (st) { WVM2_; } else { WVM0_; }
        BAR_;
    }

    if (MODE == 3) {
        // swapped layout: per (i,j): row m = ..+i*16+md (fixed per lane),
        // cols n = ..+j*16+qd*4 + {0..3} consecutive -> vector f32x4 path.
        #pragma unroll
        for (int i = 0; i < 8; ++i) {
            const int m = m0 + wr * 128 + i * 16 + md;
            const int64_t rowo = ooff + (int64_t)m * ldo;
            #pragma unroll
            for (int j = 0; j < 4; ++j) {
                const int n = n0 + wc * 64 + j * 16 + qd * 4;
                f4_t v = acc[i][j];
                const f4_t bq = *(const f4_t*)&bias[n];
                v.x += bq.x; v.y += bq.y; v.z += bq.z; v.w += bq.w;
                const f4_t r4 = *(const f4_t*)&resid[ooff + (int64_t)m * ldr + n];
                v.x += r4.x; v.y += r4.y; v.z += r4.z; v.w += r4.w;
                *(f4_t*)&((float*)outv)[rowo + n] = v;
            }
        }
    } else {
        // unswapped layout (r3-measured): col = lane&15, row = (lane>>4)*4 + reg
        #pragma unroll
        for (int i = 0; i < 8; ++i) {
            #pragma unroll
            for (int rr = 0; rr < 4; ++rr) {
                const int m = m0 + wr * 128 + i * 16 + qd * 4 + rr;
                const int64_t rowo = ooff + (int64_t)m * ldo;
                #pragma unroll
                for (int j = 0; j < 4; ++j) {
                    const int n = n0 + wc * 64 + j * 16 + md;
                    float v = acc[i][j][rr];
                    v += bias[n];
                    if (MODE == 2) v = fast_gelu(v);
                    ((u16*)outv)[rowo + n] = f2bf_fast(v);
                }
            }
        }
    }
}

#undef LD_
#undef FENCE_
#undef BAR_
#undef WVM8_
#undef WVM2_
#undef WVM0_
#undef MFMA_
#undef MM16U_
#undef MM16S_
#undef MM16_
#undef STGA_
#undef STGB_

// ------------------------------- launcher --------------------------------------
extern "C" void kernel_launch(void* const* d_in, const int* in_sizes, int n_in,
                              void* d_out, int out_size, void* d_ws, size_t ws_size,
                              hipStream_t stream) {
    const float* x      = (const float*)d_in[0];
    const float* n1w    = (const float*)d_in[1];
    const float* n1b    = (const float*)d_in[2];
    const float* qkv_w  = (const float*)d_in[3];
    const float* qkv_b  = (const float*)d_in[4];
    const float* lnk_w  = (const float*)d_in[5];
    const float* lnk_b  = (const float*)d_in[6];
    const float* lnv_w  = (const float*)d_in[7];
    const float* lnv_b  = (const float*)d_in[8];
    const float* proj_w = (const float*)d_in[9];
    const float* proj_b = (const float*)d_in[10];
    const float* n2w    = (const float*)d_in[11];
    const float* n2b    = (const float*)d_in[12];
    const float* w1     = (const float*)d_in[13];
    const float* b1     = (const float*)d_in[14];
    const float* w2     = (const float*)d_in[15];
    const float* b2     = (const float*)d_in[16];
    float* out = (float*)d_out;                 // x1 lives here, then final

    // workspace layout (~209.2 MB)
    char* ws = (char*)d_ws;
    u16*  qkvWT = (u16*)(ws + 0);               // [1536,512] bf16   1.5 MB
    u16*  projT = (u16*)(ws + 1572864);         // [512,512]         0.5 MB
    u16*  w1T   = (u16*)(ws + 2097152);         // [2048,512]        2 MB
    u16*  w2T   = (u16*)(ws + 4194304);         // [512,2048]        2 MB
    u16*  ctxN  = (u16*)(ws + 7340032);         // [16,128,128] bf16 0.5 MB
    u16*  bufA  = (u16*)(ws + 7864320);         // xn / wqT / h      32 MB
    u16*  qkv   = (u16*)(ws + 41418752);        // [32768,1536] bf16 96 MB
    u16*  hid   = (u16*)(ws + 41418752);        // overlays qkv (dead by then)
    float* ctxP = (float*)(ws + 142082048);     // [16,64,128,128] f32 64 MB (old kT/vT)
    // overlay inside bufA (xn dead after qkv-gemm; h written after proj-fused):
    u16*  wqT   = (u16*)(ws + 7864320);         // [4][512,512] bf16 W_eff^T 2 MB

    dim3 blk(256);
    dim3 blk5(512);

    // weights -> bf16 transposed [N,K] (LDS-tiled, coalesced both sides)
    wtrans<<<dim3((512 / 64) * (1536 / 64)), blk, 0, stream>>>(qkv_w, qkvWT, 512, 1536);
    wtrans<<<dim3((512 / 64) * (512 / 64)),  blk, 0, stream>>>(proj_w, projT, 512, 512);
    wtrans<<<dim3((512 / 64) * (2048 / 64)), blk, 0, stream>>>(w1, w1T, 512, 2048);
    wtrans<<<dim3((2048 / 64) * (512 / 64)), blk, 0, stream>>>(w2, w2T, 2048, 512);

    // LN1: x -> xn (bufA)
    ln_rows<<<dim3(M_), blk, 0, stream>>>(x, n1w, n1b, bufA);

    // qkv = xn @ qkv_w + qkv_b   [32768,1536] bf16
    gemm256<1, 512><<<dim3(M_ / 256, 1536 / 256, 1), blk5, 0, stream>>>(
        bufA, 512, 0, qkvWT, 512, 0, (void*)qkv, 1536, 0, qkv_b, nullptr, 0);

    // fused LN(k),LN(v) + ctx partials (64 n-chunks of 128 rows)
    lnkv_ctx<<<dim3(B_ * H_, 64), blk, 0, stream>>>(
        qkv, lnk_w, lnk_b, lnv_w, lnv_b, ctxP);
    // reduce 64 partials + SCALE -> ctxN[bh][d][e] bf16
    ctxfin<<<dim3(16 * 16384 / 256), blk, 0, stream>>>(ctxP, ctxN);

    // W_eff^T[b][j, h*128+d] = sum_e proj_w[h*128+e, j] * ctx_scaled[bh][d,e]
    gemm_bt<0, 128, 4><<<dim3(4, 1, 16), blk, 0, stream>>>(
        projT, 512, 0, 128,  ctxN, 128, 65536, 16384,
        (void*)wqT, 512, 262144, 128,  nullptr, nullptr, 0);

    // x1 = q @ W_eff + proj_b + x  -> d_out (fp32)   [attn+proj fused, z=batch]
    gemm256<3, 512><<<dim3(N_ / 256, 512 / 256, B_), blk5, 0, stream>>>(
        qkv, 1536, (int64_t)N_ * 1536,  wqT, 512, 262144,
        (void*)out, 512, (int64_t)N_ * 512,  proj_b, x, 512);

    // LN2: x1 -> h (bufA)
    ln_rows<<<dim3(M_), blk, 0, stream>>>(out, n2w, n2b, bufA);

    // hid = gelu(h @ w1 + b1)  [32768,2048] bf16
    gemm256<2, 512><<<dim3(M_ / 256, HID_ / 256, 1), blk5, 0, stream>>>(
        bufA, 512, 0, w1T, 512, 0, (void*)hid, HID_, 0, b1, nullptr, 0);

    // out = x1 + hid @ w2 + b2   (resid = d_out read-before-write per thread)
    gemm256<3, 2048><<<dim3(M_ / 256, 512 / 256, 1), blk5, 0, stream>>>(
        hid, HID_, 0, w2T, HID_, 0, (void*)out, 512, 0, b2, out, 512);
}